// Round 1
// baseline (1296.417 us; speedup 1.0000x reference)
//
#include <hip/hip_runtime.h>

// PocketGNN on MI355X.
// Design:
//  - EdgeConv first matmul moved to nodes: A = x@(w1t-w1b)+b1, B = x@w1b (16x less FLOPs)
//  - h = relu(A[dst]+B[src]) per edge; m = h@w2+b2 via split-bf16 MFMA (3 mfma: hh*wh+hl*wh+hh*wl,
//    error ~2^-17 => fp32-quality, needed for the 9.5e-4 abs threshold)
//  - relu(segment_max) == atomicMax(int) of positive values into zero-init buffer
//  - pool: per-graph contiguous scan (batch sorted), deterministic; classifier fp32, 64 blocks

#define NN 10000
#define NE 160000
#define NG 64
#define NP 10048  // nodes padded to multiple of 64 (157*64)

typedef __attribute__((ext_vector_type(8))) short bf16x8;
typedef __attribute__((ext_vector_type(4))) float f32x4;

static __device__ __forceinline__ unsigned short f2bf(float f) {
    union { float f; unsigned u; } v; v.f = f;
    unsigned r = v.u + 0x7fffu + ((v.u >> 16) & 1u);   // round-to-nearest-even
    return (unsigned short)(r >> 16);
}
static __device__ __forceinline__ float bf2f(unsigned short b) {
    union { unsigned u; float f; } v; v.u = ((unsigned)b) << 16;
    return v.f;
}

// Build WcT (split hi/lo) [512][C]: cols 0..255 = (w1t-w1b)^T, 256..511 = w1b^T.
// Build w2T (split) [256][256] = w2^T. Transposed storage => contiguous bf16x8 B-fragments.
__global__ void prep_weights(const float* __restrict__ w1, const float* __restrict__ w2, int C,
                             unsigned short* __restrict__ WcTh, unsigned short* __restrict__ WcTl,
                             unsigned short* __restrict__ w2Th, unsigned short* __restrict__ w2Tl) {
    int total1 = 512 * C;
    int total = total1 + 256 * 256;
    for (int i = blockIdx.x * blockDim.x + threadIdx.x; i < total; i += gridDim.x * blockDim.x) {
        if (i < total1) {
            int n = i / C, k = i - n * C;
            float v = (n < 256) ? (w1[k * 256 + n] - w1[(C + k) * 256 + n])
                                : w1[(C + k) * 256 + (n - 256)];
            unsigned short h = f2bf(v);
            WcTh[n * C + k] = h;
            WcTl[n * C + k] = f2bf(v - bf2f(h));
        } else {
            int j = i - total1;
            int n = j >> 8, k = j & 255;
            float v = w2[k * 256 + n];
            unsigned short h = f2bf(v);
            w2Th[n * 256 + k] = h;
            w2Tl[n * 256 + k] = f2bf(v - bf2f(h));
        }
    }
}

// fp32 [N,C] -> bf16 hi/lo [NP,C], pad rows zeroed
__global__ void split_rows(const float* __restrict__ src, int C,
                           unsigned short* __restrict__ xh, unsigned short* __restrict__ xl) {
    int total = NP * C;
    for (int i = blockIdx.x * blockDim.x + threadIdx.x; i < total; i += gridDim.x * blockDim.x) {
        int row = i / C;
        float v = (row < NN) ? src[i] : 0.f;
        unsigned short h = f2bf(v);
        xh[i] = h;
        xl[i] = f2bf(v - bf2f(h));
    }
}

__global__ void zero_f32(float* __restrict__ p, int n) {
    for (int i = blockIdx.x * blockDim.x + threadIdx.x; i < n; i += gridDim.x * blockDim.x)
        p[i] = 0.f;
}

// AB[NP,512] = x @ [Wc_A | Wc_B], +b1 on cols<256. Split-bf16, direct global frag loads.
template <int C>
__global__ __launch_bounds__(256) void node_gemm(
    const unsigned short* __restrict__ xh, const unsigned short* __restrict__ xl,
    const unsigned short* __restrict__ WTh, const unsigned short* __restrict__ WTl,
    const float* __restrict__ b1, float* __restrict__ AB) {
    const int tid = threadIdx.x;
    const int wave = tid >> 6, lane = tid & 63;
    const int lrow = lane & 15, lk = (lane >> 4) * 8;
    const int r0 = blockIdx.x * 64 + wave * 16;
    const int c0 = blockIdx.y * 64;

    const unsigned short* ah_p = xh + (size_t)(r0 + lrow) * C + lk;
    const unsigned short* al_p = xl + (size_t)(r0 + lrow) * C + lk;

    f32x4 acc[4] = {};
    for (int kk = 0; kk < C; kk += 32) {
        bf16x8 ah = *(const bf16x8*)(ah_p + kk);
        bf16x8 al = *(const bf16x8*)(al_p + kk);
#pragma unroll
        for (int t = 0; t < 4; ++t) {
            const size_t boff = (size_t)(c0 + t * 16 + lrow) * C + kk + lk;
            bf16x8 bh = *(const bf16x8*)(WTh + boff);
            bf16x8 bl = *(const bf16x8*)(WTl + boff);
            acc[t] = __builtin_amdgcn_mfma_f32_16x16x32_bf16(ah, bh, acc[t], 0, 0, 0);
            acc[t] = __builtin_amdgcn_mfma_f32_16x16x32_bf16(al, bh, acc[t], 0, 0, 0);
            acc[t] = __builtin_amdgcn_mfma_f32_16x16x32_bf16(ah, bl, acc[t], 0, 0, 0);
        }
    }
#pragma unroll
    for (int t = 0; t < 4; ++t) {
        const int col = c0 + t * 16 + lrow;
        const float bias = (col < 256) ? b1[col] : 0.f;
#pragma unroll
        for (int j = 0; j < 4; ++j) {
            const int row = r0 + (lane >> 4) * 4 + j;
            AB[(size_t)row * 512 + col] = acc[t][j] + bias;
        }
    }
}

// Fused edge kernel: h = relu(A[dst]+B[src]) -> split to LDS -> h@w2+b2 -> atomicMax(y[dst])
__global__ __launch_bounds__(256) void edge_gemm(
    const float* __restrict__ AB,
    const int* __restrict__ srcI, const int* __restrict__ dstI,
    const unsigned short* __restrict__ w2Th, const unsigned short* __restrict__ w2Tl,
    const float* __restrict__ b2, float* __restrict__ y) {
    __shared__ unsigned short hh[64][256];  // 32 KB
    __shared__ unsigned short hl[64][256];  // 32 KB
    const int tid = threadIdx.x;
    const int e0 = blockIdx.x * 64;

    // phase 1: gather + relu + split. One wave per edge per pass, coalesced row reads.
    for (int pass = 0; pass < 16; ++pass) {
        const int el = pass * 4 + (tid >> 6);
        const int e = e0 + el;
        const int s = srcI[e], d = dstI[e];
        const int k = tid & 63;
        const float* arow = AB + (size_t)d * 512;
        const float* brow = AB + (size_t)s * 512 + 256;
#pragma unroll
        for (int j = 0; j < 4; ++j) {
            const int kk = k + 64 * j;
            const float hv = fmaxf(arow[kk] + brow[kk], 0.f);
            const unsigned short hi_ = f2bf(hv);
            hh[el][kk] = hi_;
            hl[el][kk] = f2bf(hv - bf2f(hi_));
        }
    }
    __syncthreads();

    // phase 2: 64x256 MFMA tile, K=256. Wave w: edges w*16..+16, all 256 cols (16 tiles).
    const int wave = tid >> 6, lane = tid & 63;
    const int lrow = lane & 15, lk = (lane >> 4) * 8;

    f32x4 acc[16] = {};
    for (int kk = 0; kk < 256; kk += 32) {
        bf16x8 ah = *(const bf16x8*)(&hh[wave * 16 + lrow][kk + lk]);
        bf16x8 al = *(const bf16x8*)(&hl[wave * 16 + lrow][kk + lk]);
#pragma unroll
        for (int t = 0; t < 16; ++t) {
            const size_t boff = (size_t)(t * 16 + lrow) * 256 + kk + lk;
            bf16x8 bh = *(const bf16x8*)(w2Th + boff);
            bf16x8 bl = *(const bf16x8*)(w2Tl + boff);
            acc[t] = __builtin_amdgcn_mfma_f32_16x16x32_bf16(ah, bh, acc[t], 0, 0, 0);
            acc[t] = __builtin_amdgcn_mfma_f32_16x16x32_bf16(al, bh, acc[t], 0, 0, 0);
            acc[t] = __builtin_amdgcn_mfma_f32_16x16x32_bf16(ah, bl, acc[t], 0, 0, 0);
        }
    }

    // epilogue: +b2, scatter-max positives (positive floats order like ints; y pre-zeroed)
    const int erow = wave * 16 + (lane >> 4) * 4;
    int dsts[4];
#pragma unroll
    for (int j = 0; j < 4; ++j) dsts[j] = dstI[e0 + erow + j];
#pragma unroll
    for (int t = 0; t < 16; ++t) {
        const int col = t * 16 + lrow;
        const float bias = b2[col];
#pragma unroll
        for (int j = 0; j < 4; ++j) {
            const float v = acc[t][j] + bias;
            if (v > 0.f)
                atomicMax((int*)(y + (size_t)dsts[j] * 256 + col), __float_as_int(v));
        }
    }
}

// per-graph mean+max pool; batch sorted => contiguous segments via binary search
__global__ void pool_kernel(const float* __restrict__ y, const int* __restrict__ batch,
                            float* __restrict__ pooled) {
    const int g = blockIdx.x;
    __shared__ int slo, shi;
    if (threadIdx.x == 0) {
        int lo = 0, hi = NN;
        while (lo < hi) { int m = (lo + hi) >> 1; if (batch[m] < g) lo = m + 1; else hi = m; }
        slo = lo;
        int lo2 = lo, hi2 = NN;
        while (lo2 < hi2) { int m = (lo2 + hi2) >> 1; if (batch[m] < g + 1) lo2 = m + 1; else hi2 = m; }
        shi = lo2;
    }
    __syncthreads();
    const int lo = slo, hi = shi, c = threadIdx.x;
    float s0 = 0.f, s1 = 0.f, s2 = 0.f, s3 = 0.f;
    float m0 = 0.f, m1 = 0.f, m2 = 0.f, m3 = 0.f;  // y >= 0, so 0 is a safe identity
    int n = lo;
    for (; n + 4 <= hi; n += 4) {
        float v0 = y[(size_t)(n + 0) * 256 + c];
        float v1 = y[(size_t)(n + 1) * 256 + c];
        float v2 = y[(size_t)(n + 2) * 256 + c];
        float v3 = y[(size_t)(n + 3) * 256 + c];
        s0 += v0; s1 += v1; s2 += v2; s3 += v3;
        m0 = fmaxf(m0, v0); m1 = fmaxf(m1, v1); m2 = fmaxf(m2, v2); m3 = fmaxf(m3, v3);
    }
    for (; n < hi; ++n) {
        float v = y[(size_t)n * 256 + c];
        s0 += v; m0 = fmaxf(m0, v);
    }
    const float s = (s0 + s1) + (s2 + s3);
    const float mx = fmaxf(fmaxf(m0, m1), fmaxf(m2, m3));
    const int cnt = hi - lo;
    pooled[g * 512 + c] = cnt ? s / (float)cnt : 0.f;
    pooled[g * 512 + 256 + c] = cnt ? mx : 0.f;
}

// tiny MLP: 512->256 relu -> 256->64 relu -> 64->1 ; one block per graph, fp32
__global__ void classifier(const float* __restrict__ pooled,
                           const float* __restrict__ w1, const float* __restrict__ b1,
                           const float* __restrict__ w2, const float* __restrict__ b2,
                           const float* __restrict__ w3, const float* __restrict__ b3,
                           float* __restrict__ out) {
    const int g = blockIdx.x;
    __shared__ float ph[512];
    __shared__ float o1[256];
    __shared__ float o2[64];
    const int t = threadIdx.x;  // 256 threads
    ph[t] = pooled[g * 512 + t];
    ph[t + 256] = pooled[g * 512 + 256 + t];
    __syncthreads();
    float s = 0.f;
    for (int k = 0; k < 512; ++k) s += ph[k] * w1[k * 256 + t];
    o1[t] = fmaxf(s + b1[t], 0.f);
    __syncthreads();
    if (t < 64) {
        float s2 = 0.f;
        for (int k = 0; k < 256; ++k) s2 += o1[k] * w2[k * 64 + t];
        o2[t] = fmaxf(s2 + b2[t], 0.f);
    }
    __syncthreads();
    if (t < 64) {
        float v = o2[t] * w3[t];
        for (int off = 32; off; off >>= 1) v += __shfl_down(v, off);
        if (t == 0) out[g] = v + b3[0];
    }
}

extern "C" void kernel_launch(void* const* d_in, const int* in_sizes, int n_in,
                              void* d_out, int out_size, void* d_ws, size_t ws_size,
                              hipStream_t stream) {
    (void)in_sizes; (void)n_in; (void)out_size; (void)ws_size;
    const float* x0 = (const float*)d_in[0];
    const int* eidx = (const int*)d_in[1];
    const int* batch = (const int*)d_in[2];
    const int* srcI = eidx;            // edge_index[0] = src
    const int* dstI = eidx + NE;       // edge_index[1] = dst

    char* ws = (char*)d_ws;
    size_t off = 0;
    auto alloc = [&](size_t bytes) -> void* {
        void* p = ws + off;
        off += (bytes + 255) & ~(size_t)255;
        return p;
    };
    unsigned short* xh = (unsigned short*)alloc((size_t)NP * 256 * 2);
    unsigned short* xl = (unsigned short*)alloc((size_t)NP * 256 * 2);
    float* AB = (float*)alloc((size_t)NP * 512 * 4);
    float* y  = (float*)alloc((size_t)NP * 256 * 4);
    unsigned short* WcTh = (unsigned short*)alloc(512 * 256 * 2);
    unsigned short* WcTl = (unsigned short*)alloc(512 * 256 * 2);
    unsigned short* w2Th = (unsigned short*)alloc(256 * 256 * 2);
    unsigned short* w2Tl = (unsigned short*)alloc(256 * 256 * 2);
    float* pooled = (float*)alloc(64 * 512 * 4);

    const float* lw[3][4] = {
        {(const float*)d_in[3],  (const float*)d_in[4],  (const float*)d_in[5],  (const float*)d_in[6]},
        {(const float*)d_in[7],  (const float*)d_in[8],  (const float*)d_in[9],  (const float*)d_in[10]},
        {(const float*)d_in[11], (const float*)d_in[12], (const float*)d_in[13], (const float*)d_in[14]},
    };

    split_rows<<<dim3(512), dim3(256), 0, stream>>>(x0, 128, xh, xl);

    for (int l = 0; l < 3; ++l) {
        const int C = (l == 0) ? 128 : 256;
        prep_weights<<<dim3(256), dim3(256), 0, stream>>>(lw[l][0], lw[l][2], C, WcTh, WcTl, w2Th, w2Tl);
        if (C == 128)
            node_gemm<128><<<dim3(NP / 64, 8), dim3(256), 0, stream>>>(xh, xl, WcTh, WcTl, lw[l][1], AB);
        else
            node_gemm<256><<<dim3(NP / 64, 8), dim3(256), 0, stream>>>(xh, xl, WcTh, WcTl, lw[l][1], AB);
        zero_f32<<<dim3(1024), dim3(256), 0, stream>>>(y, NP * 256);
        edge_gemm<<<dim3(NE / 64), dim3(256), 0, stream>>>(AB, srcI, dstI, w2Th, w2Tl, lw[l][3], y);
        if (l < 2)
            split_rows<<<dim3(1024), dim3(256), 0, stream>>>(y, 256, xh, xl);
    }

    pool_kernel<<<dim3(NG), dim3(256), 0, stream>>>(y, batch, pooled);
    classifier<<<dim3(NG), dim3(256), 0, stream>>>(pooled,
        (const float*)d_in[15], (const float*)d_in[16],
        (const float*)d_in[17], (const float*)d_in[18],
        (const float*)d_in[19], (const float*)d_in[20], (float*)d_out);
}

// Round 2
// 639.337 us; speedup vs baseline: 2.0278x; 2.0278x over previous
//
#include <hip/hip_runtime.h>

// PocketGNN on MI355X — round 2.
// - EdgeConv first matmul on nodes: A = x@(w1t-w1b)+b1, B = x@w1b (16x fewer FLOPs)
// - h = relu(A[dst]+B[src]); m = h@w2+b2 via 2-mfma split (hh*wh + hl*wh): h carries
//   fp32-quality via hi/lo split, w2 single bf16 (~2^-9 rel err, far under threshold)
// - relu(segment_max) == atomicMax(int) of positives into zero-init buffer
// - edge_gemm: EB=32 edges/block, w2 B-frags amortized across edge tiles,
//   LDS rows padded to 264 (2-way banks), 4 blocks/CU

#define NN 10000
#define NE 160000
#define NG 64
#define NP 10048  // nodes padded to 64

typedef __attribute__((ext_vector_type(8))) short bf16x8;
typedef __attribute__((ext_vector_type(4))) float f32x4;
typedef __attribute__((ext_vector_type(4))) unsigned short u16x4;

static __device__ __forceinline__ unsigned short f2bf(float f) {
    union { float f; unsigned u; } v; v.f = f;
    unsigned r = v.u + 0x7fffu + ((v.u >> 16) & 1u);   // RNE
    return (unsigned short)(r >> 16);
}
static __device__ __forceinline__ float bf2f(unsigned short b) {
    union { unsigned u; float f; } v; v.u = ((unsigned)b) << 16;
    return v.f;
}

// WcTh [512][C]: rows 0..255 = (w1t-w1b)^T, 256..511 = w1b^T.  w2Th [256][256] = w2^T.
__global__ void prep_weights(const float* __restrict__ w1, const float* __restrict__ w2, int C,
                             unsigned short* __restrict__ WcTh, unsigned short* __restrict__ w2Th) {
    int total1 = 512 * C;
    int total = total1 + 256 * 256;
    for (int i = blockIdx.x * blockDim.x + threadIdx.x; i < total; i += gridDim.x * blockDim.x) {
        if (i < total1) {
            int n = i / C, k = i - n * C;
            float v = (n < 256) ? (w1[k * 256 + n] - w1[(C + k) * 256 + n])
                                : w1[(C + k) * 256 + (n - 256)];
            WcTh[n * C + k] = f2bf(v);
        } else {
            int j = i - total1;
            int n = j >> 8, k = j & 255;
            w2Th[n * 256 + k] = f2bf(w2[k * 256 + n]);
        }
    }
}

// fp32 [N,C] -> bf16 hi/lo [NP,C], pad rows zeroed
__global__ void split_rows(const float* __restrict__ src, int C,
                           unsigned short* __restrict__ xh, unsigned short* __restrict__ xl) {
    int total = NP * C;
    for (int i = blockIdx.x * blockDim.x + threadIdx.x; i < total; i += gridDim.x * blockDim.x) {
        int row = i / C;
        float v = (row < NN) ? src[i] : 0.f;
        unsigned short h = f2bf(v);
        xh[i] = h;
        xl[i] = f2bf(v - bf2f(h));
    }
}

__global__ void zero_f32(float* __restrict__ p, int n) {
    for (int i = blockIdx.x * blockDim.x + threadIdx.x; i < n; i += gridDim.x * blockDim.x)
        p[i] = 0.f;
}

// AB[NP,512] = x @ [Wc_A | Wc_B], +b1 on cols<256.
// Block: 64 rows x 256 cols (blockIdx.y halves), wave owns 64 cols; B amortized over m.
template <int C>
__global__ __launch_bounds__(256) void node_gemm(
    const unsigned short* __restrict__ xh, const unsigned short* __restrict__ xl,
    const unsigned short* __restrict__ WTh, const float* __restrict__ b1,
    float* __restrict__ AB) {
    const int tid = threadIdx.x;
    const int wave = tid >> 6, lane = tid & 63;
    const int lrow = lane & 15, lk = (lane >> 4) * 8;
    const int r0 = blockIdx.x * 64;
    const int c0 = blockIdx.y * 256 + wave * 64;

    f32x4 acc[4][4] = {};
    for (int kk = 0; kk < C; kk += 32) {
        bf16x8 ah[4], al[4];
#pragma unroll
        for (int m = 0; m < 4; ++m) {
            const size_t aoff = (size_t)(r0 + m * 16 + lrow) * C + kk + lk;
            ah[m] = *(const bf16x8*)(xh + aoff);
            al[m] = *(const bf16x8*)(xl + aoff);
        }
#pragma unroll
        for (int t = 0; t < 4; ++t) {
            bf16x8 bh = *(const bf16x8*)(WTh + (size_t)(c0 + t * 16 + lrow) * C + kk + lk);
#pragma unroll
            for (int m = 0; m < 4; ++m) {
                acc[m][t] = __builtin_amdgcn_mfma_f32_16x16x32_bf16(ah[m], bh, acc[m][t], 0, 0, 0);
                acc[m][t] = __builtin_amdgcn_mfma_f32_16x16x32_bf16(al[m], bh, acc[m][t], 0, 0, 0);
            }
        }
    }
#pragma unroll
    for (int t = 0; t < 4; ++t) {
        const int col = c0 + t * 16 + lrow;
        const float bias = (col < 256) ? b1[col] : 0.f;
#pragma unroll
        for (int m = 0; m < 4; ++m) {
#pragma unroll
            for (int j = 0; j < 4; ++j) {
                const int row = r0 + m * 16 + (lane >> 4) * 4 + j;
                AB[(size_t)row * 512 + col] = acc[m][t][j] + bias;
            }
        }
    }
}

// Fused edge kernel, EB=32 edges/block:
//  stage: h = relu(A[dst]+B[src]) split hi/lo -> LDS (padded rows)
//  gemm:  wave owns 64 cols; bh loaded once per (kk,t), reused over 2 edge-tiles
//  epi:   +b2, atomicMax positives into y[dst]
__global__ __launch_bounds__(256, 4) void edge_gemm(
    const float* __restrict__ AB,
    const int* __restrict__ srcI, const int* __restrict__ dstI,
    const unsigned short* __restrict__ w2Th,
    const float* __restrict__ b2, float* __restrict__ y) {
    __shared__ unsigned short hh[32][264];  // 16.9 KB, 2-way banks on b128 reads
    __shared__ unsigned short hl[32][264];
    const int tid = threadIdx.x;
    const int wave = tid >> 6, lane = tid & 63;
    const int e0 = blockIdx.x * 32;
    const int ew = wave * 8;  // this wave's 8 edges (local)

    // ---- stage ----
    int se[8], de[8];
#pragma unroll
    for (int i = 0; i < 8; ++i) {
        se[i] = srcI[e0 + ew + i];
        de[i] = dstI[e0 + ew + i];
    }
#pragma unroll
    for (int half = 0; half < 2; ++half) {
        float4 av[4], bv[4];
#pragma unroll
        for (int i = 0; i < 4; ++i) {
            const int el = half * 4 + i;
            av[i] = *(const float4*)(AB + (size_t)de[el] * 512 + lane * 4);
            bv[i] = *(const float4*)(AB + (size_t)se[el] * 512 + 256 + lane * 4);
        }
#pragma unroll
        for (int i = 0; i < 4; ++i) {
            const int el = half * 4 + i;
            const float h0 = fmaxf(av[i].x + bv[i].x, 0.f);
            const float h1 = fmaxf(av[i].y + bv[i].y, 0.f);
            const float h2 = fmaxf(av[i].z + bv[i].z, 0.f);
            const float h3 = fmaxf(av[i].w + bv[i].w, 0.f);
            u16x4 vh, vl;
            vh[0] = f2bf(h0); vl[0] = f2bf(h0 - bf2f(vh[0]));
            vh[1] = f2bf(h1); vl[1] = f2bf(h1 - bf2f(vh[1]));
            vh[2] = f2bf(h2); vl[2] = f2bf(h2 - bf2f(vh[2]));
            vh[3] = f2bf(h3); vl[3] = f2bf(h3 - bf2f(vh[3]));
            *(u16x4*)(&hh[ew + el][lane * 4]) = vh;
            *(u16x4*)(&hl[ew + el][lane * 4]) = vl;
        }
    }
    __syncthreads();

    // ---- gemm: M=32 (2 tiles), wave's N=64 (4 tiles), K=256 ----
    const int lrow = lane & 15, lk = (lane >> 4) * 8;
    f32x4 acc[2][4] = {};
    for (int kk = 0; kk < 256; kk += 32) {
        bf16x8 ah[2], al[2];
#pragma unroll
        for (int m = 0; m < 2; ++m) {
            ah[m] = *(const bf16x8*)(&hh[m * 16 + lrow][kk + lk]);
            al[m] = *(const bf16x8*)(&hl[m * 16 + lrow][kk + lk]);
        }
#pragma unroll
        for (int t = 0; t < 4; ++t) {
            bf16x8 bh = *(const bf16x8*)(w2Th + (size_t)(wave * 64 + t * 16 + lrow) * 256 + kk + lk);
#pragma unroll
            for (int m = 0; m < 2; ++m) {
                acc[m][t] = __builtin_amdgcn_mfma_f32_16x16x32_bf16(ah[m], bh, acc[m][t], 0, 0, 0);
                acc[m][t] = __builtin_amdgcn_mfma_f32_16x16x32_bf16(al[m], bh, acc[m][t], 0, 0, 0);
            }
        }
    }

    // ---- epilogue ----
    int dsts[2][4];
#pragma unroll
    for (int m = 0; m < 2; ++m)
#pragma unroll
        for (int j = 0; j < 4; ++j)
            dsts[m][j] = dstI[e0 + m * 16 + (lane >> 4) * 4 + j];
#pragma unroll
    for (int t = 0; t < 4; ++t) {
        const int col = wave * 64 + t * 16 + lrow;
        const float bias = b2[col];
#pragma unroll
        for (int m = 0; m < 2; ++m) {
#pragma unroll
            for (int j = 0; j < 4; ++j) {
                const float v = acc[m][t][j] + bias;
                if (v > 0.f)
                    atomicMax((int*)(y + (size_t)dsts[m][j] * 256 + col), __float_as_int(v));
            }
        }
    }
}

// per-graph mean+max pool; batch sorted => contiguous segments via binary search
__global__ void pool_kernel(const float* __restrict__ y, const int* __restrict__ batch,
                            float* __restrict__ pooled) {
    const int g = blockIdx.x;
    __shared__ int slo, shi;
    if (threadIdx.x == 0) {
        int lo = 0, hi = NN;
        while (lo < hi) { int m = (lo + hi) >> 1; if (batch[m] < g) lo = m + 1; else hi = m; }
        slo = lo;
        int lo2 = lo, hi2 = NN;
        while (lo2 < hi2) { int m = (lo2 + hi2) >> 1; if (batch[m] < g + 1) lo2 = m + 1; else hi2 = m; }
        shi = lo2;
    }
    __syncthreads();
    const int lo = slo, hi = shi, c = threadIdx.x;
    float s0 = 0.f, s1 = 0.f, s2 = 0.f, s3 = 0.f;
    float m0 = 0.f, m1 = 0.f, m2 = 0.f, m3 = 0.f;  // y >= 0 -> 0 is safe identity
    int n = lo;
    for (; n + 4 <= hi; n += 4) {
        float v0 = y[(size_t)(n + 0) * 256 + c];
        float v1 = y[(size_t)(n + 1) * 256 + c];
        float v2 = y[(size_t)(n + 2) * 256 + c];
        float v3 = y[(size_t)(n + 3) * 256 + c];
        s0 += v0; s1 += v1; s2 += v2; s3 += v3;
        m0 = fmaxf(m0, v0); m1 = fmaxf(m1, v1); m2 = fmaxf(m2, v2); m3 = fmaxf(m3, v3);
    }
    for (; n < hi; ++n) {
        float v = y[(size_t)n * 256 + c];
        s0 += v; m0 = fmaxf(m0, v);
    }
    const float s = (s0 + s1) + (s2 + s3);
    const float mx = fmaxf(fmaxf(m0, m1), fmaxf(m2, m3));
    const int cnt = hi - lo;
    pooled[g * 512 + c] = cnt ? s / (float)cnt : 0.f;
    pooled[g * 512 + 256 + c] = cnt ? mx : 0.f;
}

// tiny MLP: 512->256 relu -> 256->64 relu -> 64->1 ; one block per graph, fp32
__global__ void classifier(const float* __restrict__ pooled,
                           const float* __restrict__ w1, const float* __restrict__ b1,
                           const float* __restrict__ w2, const float* __restrict__ b2,
                           const float* __restrict__ w3, const float* __restrict__ b3,
                           float* __restrict__ out) {
    const int g = blockIdx.x;
    __shared__ float ph[512];
    __shared__ float o1[256];
    __shared__ float o2[64];
    const int t = threadIdx.x;  // 256 threads
    ph[t] = pooled[g * 512 + t];
    ph[t + 256] = pooled[g * 512 + 256 + t];
    __syncthreads();
    float s = 0.f;
    for (int k = 0; k < 512; ++k) s += ph[k] * w1[k * 256 + t];
    o1[t] = fmaxf(s + b1[t], 0.f);
    __syncthreads();
    if (t < 64) {
        float s2 = 0.f;
        for (int k = 0; k < 256; ++k) s2 += o1[k] * w2[k * 64 + t];
        o2[t] = fmaxf(s2 + b2[t], 0.f);
    }
    __syncthreads();
    if (t < 64) {
        float v = o2[t] * w3[t];
        for (int off = 32; off; off >>= 1) v += __shfl_down(v, off);
        if (t == 0) out[g] = v + b3[0];
    }
}

extern "C" void kernel_launch(void* const* d_in, const int* in_sizes, int n_in,
                              void* d_out, int out_size, void* d_ws, size_t ws_size,
                              hipStream_t stream) {
    (void)in_sizes; (void)n_in; (void)out_size; (void)ws_size;
    const float* x0 = (const float*)d_in[0];
    const int* eidx = (const int*)d_in[1];
    const int* batch = (const int*)d_in[2];
    const int* srcI = eidx;            // edge_index[0] = src
    const int* dstI = eidx + NE;       // edge_index[1] = dst

    char* ws = (char*)d_ws;
    size_t off = 0;
    auto alloc = [&](size_t bytes) -> void* {
        void* p = ws + off;
        off += (bytes + 255) & ~(size_t)255;
        return p;
    };
    unsigned short* xh = (unsigned short*)alloc((size_t)NP * 256 * 2);
    unsigned short* xl = (unsigned short*)alloc((size_t)NP * 256 * 2);
    float* AB = (float*)alloc((size_t)NP * 512 * 4);
    float* y  = (float*)alloc((size_t)NP * 256 * 4);
    unsigned short* WcTh = (unsigned short*)alloc(512 * 256 * 2);
    unsigned short* w2Th = (unsigned short*)alloc(256 * 256 * 2);
    float* pooled = (float*)alloc(64 * 512 * 4);

    const float* lw[3][4] = {
        {(const float*)d_in[3],  (const float*)d_in[4],  (const float*)d_in[5],  (const float*)d_in[6]},
        {(const float*)d_in[7],  (const float*)d_in[8],  (const float*)d_in[9],  (const float*)d_in[10]},
        {(const float*)d_in[11], (const float*)d_in[12], (const float*)d_in[13], (const float*)d_in[14]},
    };

    split_rows<<<dim3(512), dim3(256), 0, stream>>>(x0, 128, xh, xl);

    for (int l = 0; l < 3; ++l) {
        const int C = (l == 0) ? 128 : 256;
        prep_weights<<<dim3(256), dim3(256), 0, stream>>>(lw[l][0], lw[l][2], C, WcTh, w2Th);
        if (C == 128)
            node_gemm<128><<<dim3(NP / 64, 2), dim3(256), 0, stream>>>(xh, xl, WcTh, lw[l][1], AB);
        else
            node_gemm<256><<<dim3(NP / 64, 2), dim3(256), 0, stream>>>(xh, xl, WcTh, lw[l][1], AB);
        zero_f32<<<dim3(1024), dim3(256), 0, stream>>>(y, NP * 256);
        edge_gemm<<<dim3(NE / 32), dim3(256), 0, stream>>>(AB, srcI, dstI, w2Th, lw[l][3], y);
        if (l < 2)
            split_rows<<<dim3(1024), dim3(256), 0, stream>>>(y, 256, xh, xl);
    }

    pool_kernel<<<dim3(NG), dim3(256), 0, stream>>>(y, batch, pooled);
    classifier<<<dim3(NG), dim3(256), 0, stream>>>(pooled,
        (const float*)d_in[15], (const float*)d_in[16],
        (const float*)d_in[17], (const float*)d_in[18],
        (const float*)d_in[19], (const float*)d_in[20], (float*)d_out);
}

// Round 3
// 574.633 us; speedup vs baseline: 2.2561x; 1.1126x over previous
//
#include <hip/hip_runtime.h>

// PocketGNN on MI355X — round 3.
// - EdgeConv first matmul on nodes: A = x@(w1t-w1b)+b1, B = x@w1b (16x fewer FLOPs)
// - All GEMMs in f16 single-MFMA (2^-11 per-operand rounding; measured bf16-single gave
//   4.9e-4, f16 predicted ~2e-4 vs 9.5e-4 threshold)
// - Edges counting-sorted by dst (once, reused 3 layers): A-gather gets L1 reuse,
//   epilogue chain-reduces same-dst rows in registers before atomicMax
// - relu(segment_max) == atomicMax(int) of positives into zero-init buffer
// - LDS h-tile XOR-swizzled ((row&7)<<3 on ushort index): conflict-free b128 reads

#define NN 10000
#define NE 160000
#define NG 64
#define NP 10048  // nodes padded to 64

typedef __attribute__((ext_vector_type(8))) _Float16 f16x8;
typedef __attribute__((ext_vector_type(4))) _Float16 f16x4;
typedef __attribute__((ext_vector_type(4))) float f32x4;

// ---------------- edge sort by dst (counting sort) ----------------
__global__ void hist_kernel(const int* __restrict__ dstI, int* __restrict__ hist) {
    int i = blockIdx.x * blockDim.x + threadIdx.x;
    if (i < NE) atomicAdd(&hist[dstI[i]], 1);
}

// in-place safe: cursor may alias hist
__global__ void scan_kernel(const int* __restrict__ hist, int* __restrict__ cursor) {
    __shared__ int sums[256];
    const int t = threadIdx.x;
    const int per = (NN + 255) / 256;  // 40
    const int lo = t * per, hi = (lo + per < NN) ? lo + per : NN;
    int s = 0;
    for (int i = lo; i < hi; ++i) s += hist[i];
    sums[t] = s;
    __syncthreads();
    for (int ofs = 1; ofs < 256; ofs <<= 1) {
        int add = (t >= ofs) ? sums[t - ofs] : 0;
        __syncthreads();
        sums[t] += add;
        __syncthreads();
    }
    int run = sums[t] - s;  // exclusive prefix
    for (int i = lo; i < hi; ++i) {
        int h = hist[i];      // read BEFORE aliased write
        cursor[i] = run;
        run += h;
    }
}

__global__ void scatter_kernel(const int* __restrict__ srcI, const int* __restrict__ dstI,
                               int* __restrict__ cursor,
                               int* __restrict__ se2, int* __restrict__ de2) {
    int i = blockIdx.x * blockDim.x + threadIdx.x;
    if (i < NE) {
        int d = dstI[i];
        int p = atomicAdd(&cursor[d], 1);
        se2[p] = srcI[i];
        de2[p] = d;
    }
}

// ---------------- weight prep ----------------
// WcT [512][C]: rows 0..255 = (w1t-w1b)^T, 256..511 = w1b^T.  w2T [256][256] = w2^T.
__global__ void prep_weights(const float* __restrict__ w1, const float* __restrict__ w2, int C,
                             _Float16* __restrict__ WcT, _Float16* __restrict__ w2T) {
    int total1 = 512 * C;
    int total = total1 + 256 * 256;
    for (int i = blockIdx.x * blockDim.x + threadIdx.x; i < total; i += gridDim.x * blockDim.x) {
        if (i < total1) {
            int n = i / C, k = i - n * C;
            float v = (n < 256) ? (w1[k * 256 + n] - w1[(C + k) * 256 + n])
                                : w1[(C + k) * 256 + (n - 256)];
            WcT[n * C + k] = (_Float16)v;
        } else {
            int j = i - total1;
            int n = j >> 8, k = j & 255;
            w2T[n * 256 + k] = (_Float16)w2[k * 256 + n];
        }
    }
}

// fp32 [N,C] -> f16 [NP,C], pad rows zeroed
__global__ void conv_rows(const float* __restrict__ src, int C, _Float16* __restrict__ xh) {
    int total = NP * C;
    for (int i = blockIdx.x * blockDim.x + threadIdx.x; i < total; i += gridDim.x * blockDim.x) {
        int row = i / C;
        xh[i] = (_Float16)((row < NN) ? src[i] : 0.f);
    }
}

// ---------------- node GEMM: AB[NP,512] = x @ [Wc_A | Wc_B], +b1 on cols<256 ----------------
template <int C>
__global__ __launch_bounds__(256) void node_gemm(
    const _Float16* __restrict__ xh, const _Float16* __restrict__ WT,
    const float* __restrict__ b1, float* __restrict__ AB) {
    const int wave = threadIdx.x >> 6, lane = threadIdx.x & 63;
    const int lrow = lane & 15, lk = (lane >> 4) * 8;
    const int r0 = blockIdx.x * 64;
    const int c0 = blockIdx.y * 128 + wave * 32;

    f32x4 acc[4][2] = {};
    for (int kk = 0; kk < C; kk += 32) {
        f16x8 ah[4];
#pragma unroll
        for (int m = 0; m < 4; ++m)
            ah[m] = *(const f16x8*)(xh + (size_t)(r0 + m * 16 + lrow) * C + kk + lk);
#pragma unroll
        for (int t = 0; t < 2; ++t) {
            f16x8 bh = *(const f16x8*)(WT + (size_t)(c0 + t * 16 + lrow) * C + kk + lk);
#pragma unroll
            for (int m = 0; m < 4; ++m)
                acc[m][t] = __builtin_amdgcn_mfma_f32_16x16x32_f16(ah[m], bh, acc[m][t], 0, 0, 0);
        }
    }
#pragma unroll
    for (int t = 0; t < 2; ++t) {
        const int col = c0 + t * 16 + lrow;
        const float bias = (col < 256) ? b1[col] : 0.f;
#pragma unroll
        for (int m = 0; m < 4; ++m) {
#pragma unroll
            for (int j = 0; j < 4; ++j) {
                const int row = r0 + m * 16 + (lane >> 4) * 4 + j;
                AB[(size_t)row * 512 + col] = acc[m][t][j] + bias;
            }
        }
    }
}

// ---------------- fused edge kernel (sorted-by-dst edges) ----------------
__global__ __launch_bounds__(256, 8) void edge_gemm(
    const float* __restrict__ AB,
    const int* __restrict__ se2, const int* __restrict__ de2,
    const _Float16* __restrict__ w2T,
    const float* __restrict__ b2, float* __restrict__ y) {
    __shared__ _Float16 hh[32 * 256];  // 16 KB, XOR-swizzled
    const int tid = threadIdx.x;
    const int wave = tid >> 6, lane = tid & 63;
    const int e0 = blockIdx.x * 32;
    const int ew = wave * 8;

    // ---- stage: h = relu(A[dst]+B[src]) -> f16 LDS ----
    int se[8], de[8];
#pragma unroll
    for (int i = 0; i < 8; ++i) {
        se[i] = se2[e0 + ew + i];
        de[i] = de2[e0 + ew + i];
    }
#pragma unroll
    for (int halfp = 0; halfp < 2; ++halfp) {
        float4 av[4], bv[4];
#pragma unroll
        for (int i = 0; i < 4; ++i) {
            const int el = halfp * 4 + i;
            av[i] = *(const float4*)(AB + (size_t)de[el] * 512 + lane * 4);
            bv[i] = *(const float4*)(AB + (size_t)se[el] * 512 + 256 + lane * 4);
        }
#pragma unroll
        for (int i = 0; i < 4; ++i) {
            const int el = halfp * 4 + i;
            const int row = ew + el;
            f16x4 vh;
            vh[0] = (_Float16)fmaxf(av[i].x + bv[i].x, 0.f);
            vh[1] = (_Float16)fmaxf(av[i].y + bv[i].y, 0.f);
            vh[2] = (_Float16)fmaxf(av[i].z + bv[i].z, 0.f);
            vh[3] = (_Float16)fmaxf(av[i].w + bv[i].w, 0.f);
            const int idx = (row * 256 + lane * 4) ^ ((row & 7) << 3);
            *(f16x4*)(&hh[idx]) = vh;
        }
    }
    __syncthreads();

    // ---- gemm: M=32 (2 tiles), wave's N=64 (4 tiles), K=256 ----
    const int lrow = lane & 15, lk = (lane >> 4) * 8;
    f32x4 acc[2][4] = {};
    for (int kk = 0; kk < 256; kk += 32) {
        f16x8 ah[2];
#pragma unroll
        for (int m = 0; m < 2; ++m) {
            const int row = m * 16 + lrow;
            const int idx = (row * 256 + kk + lk) ^ ((row & 7) << 3);
            ah[m] = *(const f16x8*)(&hh[idx]);
        }
#pragma unroll
        for (int t = 0; t < 4; ++t) {
            f16x8 bh = *(const f16x8*)(w2T + (size_t)(wave * 64 + t * 16 + lrow) * 256 + kk + lk);
#pragma unroll
            for (int m = 0; m < 2; ++m)
                acc[m][t] = __builtin_amdgcn_mfma_f32_16x16x32_f16(ah[m], bh, acc[m][t], 0, 0, 0);
        }
    }

    // ---- epilogue: +b2, chain-reduce same-dst rows (sorted), atomicMax positives ----
    int d4[2][4];
#pragma unroll
    for (int m = 0; m < 2; ++m)
#pragma unroll
        for (int j = 0; j < 4; ++j)
            d4[m][j] = de2[e0 + m * 16 + (lane >> 4) * 4 + j];
#pragma unroll
    for (int t = 0; t < 4; ++t) {
        const int col = wave * 64 + t * 16 + lrow;
        const float bias = b2[col];
#pragma unroll
        for (int m = 0; m < 2; ++m) {
            float v0 = acc[m][t][0] + bias;
            float v1 = acc[m][t][1] + bias;
            float v2 = acc[m][t][2] + bias;
            float v3 = acc[m][t][3] + bias;
            if (d4[m][0] == d4[m][1]) v1 = fmaxf(v1, v0);
            else if (v0 > 0.f) atomicMax((int*)(y + (size_t)d4[m][0] * 256 + col), __float_as_int(v0));
            if (d4[m][1] == d4[m][2]) v2 = fmaxf(v2, v1);
            else if (v1 > 0.f) atomicMax((int*)(y + (size_t)d4[m][1] * 256 + col), __float_as_int(v1));
            if (d4[m][2] == d4[m][3]) v3 = fmaxf(v3, v2);
            else if (v2 > 0.f) atomicMax((int*)(y + (size_t)d4[m][2] * 256 + col), __float_as_int(v2));
            if (v3 > 0.f) atomicMax((int*)(y + (size_t)d4[m][3] * 256 + col), __float_as_int(v3));
        }
    }
}

// ---------------- per-graph mean+max pool ----------------
__global__ void pool_kernel(const float* __restrict__ y, const int* __restrict__ batch,
                            float* __restrict__ pooled) {
    const int g = blockIdx.x;
    __shared__ int slo, shi;
    if (threadIdx.x == 0) {
        int lo = 0, hi = NN;
        while (lo < hi) { int m = (lo + hi) >> 1; if (batch[m] < g) lo = m + 1; else hi = m; }
        slo = lo;
        int lo2 = lo, hi2 = NN;
        while (lo2 < hi2) { int m = (lo2 + hi2) >> 1; if (batch[m] < g + 1) lo2 = m + 1; else hi2 = m; }
        shi = lo2;
    }
    __syncthreads();
    const int lo = slo, hi = shi, c = threadIdx.x;
    float s0 = 0.f, s1 = 0.f, s2 = 0.f, s3 = 0.f;
    float m0 = 0.f, m1 = 0.f, m2 = 0.f, m3 = 0.f;  // y >= 0 -> 0 safe identity
    int n = lo;
    for (; n + 4 <= hi; n += 4) {
        float v0 = y[(size_t)(n + 0) * 256 + c];
        float v1 = y[(size_t)(n + 1) * 256 + c];
        float v2 = y[(size_t)(n + 2) * 256 + c];
        float v3 = y[(size_t)(n + 3) * 256 + c];
        s0 += v0; s1 += v1; s2 += v2; s3 += v3;
        m0 = fmaxf(m0, v0); m1 = fmaxf(m1, v1); m2 = fmaxf(m2, v2); m3 = fmaxf(m3, v3);
    }
    for (; n < hi; ++n) {
        float v = y[(size_t)n * 256 + c];
        s0 += v; m0 = fmaxf(m0, v);
    }
    const float s = (s0 + s1) + (s2 + s3);
    const float mx = fmaxf(fmaxf(m0, m1), fmaxf(m2, m3));
    const int cnt = hi - lo;
    pooled[g * 512 + c] = cnt ? s / (float)cnt : 0.f;
    pooled[g * 512 + 256 + c] = cnt ? mx : 0.f;
}

// ---------------- classifier MLP ----------------
__global__ void classifier(const float* __restrict__ pooled,
                           const float* __restrict__ w1, const float* __restrict__ b1,
                           const float* __restrict__ w2, const float* __restrict__ b2,
                           const float* __restrict__ w3, const float* __restrict__ b3,
                           float* __restrict__ out) {
    const int g = blockIdx.x;
    __shared__ float ph[512];
    __shared__ float o1[256];
    __shared__ float o2[64];
    const int t = threadIdx.x;  // 256 threads
    ph[t] = pooled[g * 512 + t];
    ph[t + 256] = pooled[g * 512 + 256 + t];
    __syncthreads();
    float s = 0.f;
    for (int k = 0; k < 512; ++k) s += ph[k] * w1[k * 256 + t];
    o1[t] = fmaxf(s + b1[t], 0.f);
    __syncthreads();
    if (t < 64) {
        float s2 = 0.f;
        for (int k = 0; k < 256; ++k) s2 += o1[k] * w2[k * 64 + t];
        o2[t] = fmaxf(s2 + b2[t], 0.f);
    }
    __syncthreads();
    if (t < 64) {
        float v = o2[t] * w3[t];
        for (int off = 32; off; off >>= 1) v += __shfl_down(v, off);
        if (t == 0) out[g] = v + b3[0];
    }
}

extern "C" void kernel_launch(void* const* d_in, const int* in_sizes, int n_in,
                              void* d_out, int out_size, void* d_ws, size_t ws_size,
                              hipStream_t stream) {
    (void)in_sizes; (void)n_in; (void)out_size; (void)ws_size;
    const float* x0 = (const float*)d_in[0];
    const int* eidx = (const int*)d_in[1];
    const int* batch = (const int*)d_in[2];
    const int* srcI = eidx;            // edge_index[0] = src
    const int* dstI = eidx + NE;       // edge_index[1] = dst

    char* ws = (char*)d_ws;
    size_t off = 0;
    auto alloc = [&](size_t bytes) -> void* {
        void* p = ws + off;
        off += (bytes + 255) & ~(size_t)255;
        return p;
    };
    _Float16* xh = (_Float16*)alloc((size_t)NP * 256 * 2);
    float* AB = (float*)alloc((size_t)NP * 512 * 4);
    float* y  = (float*)alloc((size_t)NP * 256 * 4);
    _Float16* WcT = (_Float16*)alloc(512 * 256 * 2);
    _Float16* w2T = (_Float16*)alloc(256 * 256 * 2);
    float* pooled = (float*)alloc(64 * 512 * 4);
    int* hist = (int*)alloc(NN * 4);
    int* se2 = (int*)alloc(NE * 4);
    int* de2 = (int*)alloc(NE * 4);

    const float* lw[3][4] = {
        {(const float*)d_in[3],  (const float*)d_in[4],  (const float*)d_in[5],  (const float*)d_in[6]},
        {(const float*)d_in[7],  (const float*)d_in[8],  (const float*)d_in[9],  (const float*)d_in[10]},
        {(const float*)d_in[11], (const float*)d_in[12], (const float*)d_in[13], (const float*)d_in[14]},
    };

    // sort edges by dst (once, reused all layers)
    hipMemsetAsync(hist, 0, NN * 4, stream);
    hist_kernel<<<dim3((NE + 255) / 256), dim3(256), 0, stream>>>(dstI, hist);
    scan_kernel<<<dim3(1), dim3(256), 0, stream>>>(hist, hist);  // in-place exclusive scan
    scatter_kernel<<<dim3((NE + 255) / 256), dim3(256), 0, stream>>>(srcI, dstI, hist, se2, de2);

    conv_rows<<<dim3(512), dim3(256), 0, stream>>>(x0, 128, xh);

    for (int l = 0; l < 3; ++l) {
        const int C = (l == 0) ? 128 : 256;
        prep_weights<<<dim3(256), dim3(256), 0, stream>>>(lw[l][0], lw[l][2], C, WcT, w2T);
        if (C == 128)
            node_gemm<128><<<dim3(NP / 64, 4), dim3(256), 0, stream>>>(xh, WcT, lw[l][1], AB);
        else
            node_gemm<256><<<dim3(NP / 64, 4), dim3(256), 0, stream>>>(xh, WcT, lw[l][1], AB);
        hipMemsetAsync(y, 0, (size_t)NP * 256 * 4, stream);
        edge_gemm<<<dim3(NE / 32), dim3(256), 0, stream>>>(AB, se2, de2, w2T, lw[l][3], y);
        if (l < 2)
            conv_rows<<<dim3(1024), dim3(256), 0, stream>>>(y, 256, xh);
    }

    pool_kernel<<<dim3(NG), dim3(256), 0, stream>>>(y, batch, pooled);
    classifier<<<dim3(NG), dim3(256), 0, stream>>>(pooled,
        (const float*)d_in[15], (const float*)d_in[16],
        (const float*)d_in[17], (const float*)d_in[18],
        (const float*)d_in[19], (const float*)d_in[20], (float*)d_out);
}

// Round 4
// 390.810 us; speedup vs baseline: 3.3173x; 1.4704x over previous
//
#include <hip/hip_runtime.h>

// PocketGNN on MI355X — round 4.
// - EdgeConv first matmul on nodes: A = x@(w1t-w1b)+b1, B = x@w1b (16x fewer FLOPs)
// - All GEMMs f16 single-MFMA (measured absmax 2.4e-4 vs 9.5e-4 threshold)
// - Edges counting-sorted by dst; edge_gemm EB=64 with permuted edge->LDS-row mapping
//   (bit-swap involution) so each lane's 16 acc values are 16 CONSECUTIVE sorted edges
//   -> register chain-reduce per dst segment -> ~10x fewer atomics
// - launch_bounds(256,3): unified reg budget 170 -> bh double-buffer prefetch (round 3's
//   (256,8) capped at 64 regs and serialized every w2 load behind vmcnt(0))
// - relu(segment_max) == atomicMax(int) of positives into zero-init buffer

#define NN 10000
#define NE 160000
#define NG 64
#define NP 10048  // nodes padded to 64
#define EB 64     // edges per block

typedef __attribute__((ext_vector_type(8))) _Float16 f16x8;
typedef __attribute__((ext_vector_type(4))) _Float16 f16x4;
typedef __attribute__((ext_vector_type(4))) float f32x4;

// ---------------- edge sort by dst (counting sort) ----------------
__global__ void hist_kernel(const int* __restrict__ dstI, int* __restrict__ hist) {
    int i = blockIdx.x * blockDim.x + threadIdx.x;
    if (i < NE) atomicAdd(&hist[dstI[i]], 1);
}

// in-place safe: cursor may alias hist
__global__ void scan_kernel(const int* __restrict__ hist, int* __restrict__ cursor) {
    __shared__ int sums[256];
    const int t = threadIdx.x;
    const int per = (NN + 255) / 256;  // 40
    const int lo = t * per, hi = (lo + per < NN) ? lo + per : NN;
    int s = 0;
    for (int i = lo; i < hi; ++i) s += hist[i];
    sums[t] = s;
    __syncthreads();
    for (int ofs = 1; ofs < 256; ofs <<= 1) {
        int add = (t >= ofs) ? sums[t - ofs] : 0;
        __syncthreads();
        sums[t] += add;
        __syncthreads();
    }
    int run = sums[t] - s;  // exclusive prefix
    for (int i = lo; i < hi; ++i) {
        int h = hist[i];      // read BEFORE aliased write
        cursor[i] = run;
        run += h;
    }
}

__global__ void scatter_kernel(const int* __restrict__ srcI, const int* __restrict__ dstI,
                               int* __restrict__ cursor,
                               int* __restrict__ se2, int* __restrict__ de2) {
    int i = blockIdx.x * blockDim.x + threadIdx.x;
    if (i < NE) {
        int d = dstI[i];
        int p = atomicAdd(&cursor[d], 1);
        se2[p] = srcI[i];
        de2[p] = d;
    }
}

// ---------------- weight prep ----------------
// WcT [512][C]: rows 0..255 = (w1t-w1b)^T, 256..511 = w1b^T.  w2T [256][256] = w2^T.
__global__ void prep_weights(const float* __restrict__ w1, const float* __restrict__ w2, int C,
                             _Float16* __restrict__ WcT, _Float16* __restrict__ w2T) {
    int total1 = 512 * C;
    int total = total1 + 256 * 256;
    for (int i = blockIdx.x * blockDim.x + threadIdx.x; i < total; i += gridDim.x * blockDim.x) {
        if (i < total1) {
            int n = i / C, k = i - n * C;
            float v = (n < 256) ? (w1[k * 256 + n] - w1[(C + k) * 256 + n])
                                : w1[(C + k) * 256 + (n - 256)];
            WcT[n * C + k] = (_Float16)v;
        } else {
            int j = i - total1;
            int n = j >> 8, k = j & 255;
            w2T[n * 256 + k] = (_Float16)w2[k * 256 + n];
        }
    }
}

// fp32 [N,C] -> f16 [NP,C], pad rows zeroed
__global__ void conv_rows(const float* __restrict__ src, int C, _Float16* __restrict__ xh) {
    int total = NP * C;
    for (int i = blockIdx.x * blockDim.x + threadIdx.x; i < total; i += gridDim.x * blockDim.x) {
        int row = i / C;
        xh[i] = (_Float16)((row < NN) ? src[i] : 0.f);
    }
}

// ---------------- node GEMM: AB[NP,512] = x @ [Wc_A | Wc_B], +b1 on cols<256 ----------------
template <int C>
__global__ __launch_bounds__(256) void node_gemm(
    const _Float16* __restrict__ xh, const _Float16* __restrict__ WT,
    const float* __restrict__ b1, float* __restrict__ AB) {
    const int wave = threadIdx.x >> 6, lane = threadIdx.x & 63;
    const int lrow = lane & 15, lk = (lane >> 4) * 8;
    const int r0 = blockIdx.x * 64;
    const int c0 = blockIdx.y * 128 + wave * 32;

    f32x4 acc[4][2] = {};
#pragma unroll
    for (int kk = 0; kk < C; kk += 32) {
        f16x8 ah[4];
#pragma unroll
        for (int m = 0; m < 4; ++m)
            ah[m] = *(const f16x8*)(xh + (size_t)(r0 + m * 16 + lrow) * C + kk + lk);
#pragma unroll
        for (int t = 0; t < 2; ++t) {
            f16x8 bh = *(const f16x8*)(WT + (size_t)(c0 + t * 16 + lrow) * C + kk + lk);
#pragma unroll
            for (int m = 0; m < 4; ++m)
                acc[m][t] = __builtin_amdgcn_mfma_f32_16x16x32_f16(ah[m], bh, acc[m][t], 0, 0, 0);
        }
    }
#pragma unroll
    for (int t = 0; t < 2; ++t) {
        const int col = c0 + t * 16 + lrow;
        const float bias = (col < 256) ? b1[col] : 0.f;
#pragma unroll
        for (int m = 0; m < 4; ++m) {
#pragma unroll
            for (int j = 0; j < 4; ++j) {
                const int row = r0 + m * 16 + (lane >> 4) * 4 + j;
                AB[(size_t)row * 512 + col] = acc[m][t][j] + bias;
            }
        }
    }
}

// ---------------- fused edge kernel (sorted-by-dst edges) ----------------
// Edge e_local sits in LDS row perm(e_local), perm = swap(m-bits, g-bits) involution:
//   e = (m<<4)|(g<<2)|j  <->  row = (g<<4)|(m<<2)|j
// MFMA acc[m][t][j] of lane (g=lane>>4) then maps to edge g*16 + m*4 + j — i.e. each
// lane holds 16 CONSECUTIVE sorted edges -> register segment-max, few atomics.
__global__ __launch_bounds__(256, 3) void edge_gemm(
    const float* __restrict__ AB,
    const int* __restrict__ se2, const int* __restrict__ de2,
    const _Float16* __restrict__ w2T,
    const float* __restrict__ b2, float* __restrict__ y) {
    __shared__ _Float16 hh[EB * 256];  // 32 KB, XOR-swizzled
    const int tid = threadIdx.x;
    const int wave = tid >> 6, lane = tid & 63;
    const int e0 = blockIdx.x * EB;
    const int ew = wave * 16;

    // ---- stage: h = relu(A[dst]+B[src]) -> f16 LDS at permuted row ----
    int se[16], de[16];
#pragma unroll
    for (int i = 0; i < 16; ++i) {
        se[i] = se2[e0 + ew + i];
        de[i] = de2[e0 + ew + i];
    }
#pragma unroll
    for (int b = 0; b < 4; ++b) {
        float4 av[4], bv[4];
#pragma unroll
        for (int i = 0; i < 4; ++i) {
            const int el = b * 4 + i;
            av[i] = *(const float4*)(AB + (size_t)de[el] * 512 + lane * 4);
            bv[i] = *(const float4*)(AB + (size_t)se[el] * 512 + 256 + lane * 4);
        }
#pragma unroll
        for (int i = 0; i < 4; ++i) {
            // local edge id = wave*16 + b*4 + i  ->  row = b*16 + wave*4 + i (bit swap)
            const int row = b * 16 + wave * 4 + i;
            f16x4 vh;
            vh[0] = (_Float16)fmaxf(av[i].x + bv[i].x, 0.f);
            vh[1] = (_Float16)fmaxf(av[i].y + bv[i].y, 0.f);
            vh[2] = (_Float16)fmaxf(av[i].z + bv[i].z, 0.f);
            vh[3] = (_Float16)fmaxf(av[i].w + bv[i].w, 0.f);
            const int idx = (row * 256 + lane * 4) ^ ((row & 7) << 3);
            *(f16x4*)(&hh[idx]) = vh;
        }
    }
    __syncthreads();

    // ---- gemm: M=64 (4 tiles), wave's N=64 (4 tiles), K=256, bh double-buffered ----
    const int lrow = lane & 15, lk = (lane >> 4) * 8;
    const _Float16* wbase = w2T + (size_t)(wave * 64 + lrow) * 256 + lk;

    f16x8 bhA[4], bhB[4];
#pragma unroll
    for (int t = 0; t < 4; ++t)
        bhA[t] = *(const f16x8*)(wbase + (size_t)(t * 16) * 256);

    f32x4 acc[4][4] = {};
#pragma unroll
    for (int kk = 0; kk < 256; kk += 32) {
        if (kk + 32 < 256) {
#pragma unroll
            for (int t = 0; t < 4; ++t)
                bhB[t] = *(const f16x8*)(wbase + (size_t)(t * 16) * 256 + kk + 32);
        }
        f16x8 ah[4];
#pragma unroll
        for (int m = 0; m < 4; ++m) {
            const int row = m * 16 + lrow;
            const int idx = (row * 256 + kk + lk) ^ ((row & 7) << 3);
            ah[m] = *(const f16x8*)(&hh[idx]);
        }
#pragma unroll
        for (int t = 0; t < 4; ++t)
#pragma unroll
            for (int m = 0; m < 4; ++m)
                acc[m][t] = __builtin_amdgcn_mfma_f32_16x16x32_f16(ah[m], bhA[t], acc[m][t], 0, 0, 0);
#pragma unroll
        for (int t = 0; t < 4; ++t) bhA[t] = bhB[t];
    }

    // ---- epilogue: lane's 16 acc values = edges e0+g*16 .. +15; segment-max then atomics ----
    const int g = lane >> 4;
    int d[16];
#pragma unroll
    for (int k = 0; k < 16; ++k) d[k] = de2[e0 + g * 16 + k];
#pragma unroll
    for (int t = 0; t < 4; ++t) {
        const int col = wave * 64 + t * 16 + lrow;
        const float bias = b2[col];
        float run = acc[0][t][0] + bias;
        int dp = d[0];
#pragma unroll
        for (int k = 1; k < 16; ++k) {
            const float v = acc[k >> 2][t][k & 3] + bias;
            if (d[k] == dp) {
                run = fmaxf(run, v);
            } else {
                if (run > 0.f) atomicMax((int*)(y + (size_t)dp * 256 + col), __float_as_int(run));
                run = v;
                dp = d[k];
            }
        }
        if (run > 0.f) atomicMax((int*)(y + (size_t)dp * 256 + col), __float_as_int(run));
    }
}

// ---------------- per-graph mean+max pool ----------------
__global__ void pool_kernel(const float* __restrict__ y, const int* __restrict__ batch,
                            float* __restrict__ pooled) {
    const int g = blockIdx.x;
    __shared__ int slo, shi;
    if (threadIdx.x == 0) {
        int lo = 0, hi = NN;
        while (lo < hi) { int m = (lo + hi) >> 1; if (batch[m] < g) lo = m + 1; else hi = m; }
        slo = lo;
        int lo2 = lo, hi2 = NN;
        while (lo2 < hi2) { int m = (lo2 + hi2) >> 1; if (batch[m] < g + 1) lo2 = m + 1; else hi2 = m; }
        shi = lo2;
    }
    __syncthreads();
    const int lo = slo, hi = shi, c = threadIdx.x;
    float s0 = 0.f, s1 = 0.f, s2 = 0.f, s3 = 0.f;
    float m0 = 0.f, m1 = 0.f, m2 = 0.f, m3 = 0.f;  // y >= 0 -> 0 safe identity
    int n = lo;
    for (; n + 4 <= hi; n += 4) {
        float v0 = y[(size_t)(n + 0) * 256 + c];
        float v1 = y[(size_t)(n + 1) * 256 + c];
        float v2 = y[(size_t)(n + 2) * 256 + c];
        float v3 = y[(size_t)(n + 3) * 256 + c];
        s0 += v0; s1 += v1; s2 += v2; s3 += v3;
        m0 = fmaxf(m0, v0); m1 = fmaxf(m1, v1); m2 = fmaxf(m2, v2); m3 = fmaxf(m3, v3);
    }
    for (; n < hi; ++n) {
        float v = y[(size_t)n * 256 + c];
        s0 += v; m0 = fmaxf(m0, v);
    }
    const float s = (s0 + s1) + (s2 + s3);
    const float mx = fmaxf(fmaxf(m0, m1), fmaxf(m2, m3));
    const int cnt = hi - lo;
    pooled[g * 512 + c] = cnt ? s / (float)cnt : 0.f;
    pooled[g * 512 + 256 + c] = cnt ? mx : 0.f;
}

// ---------------- classifier MLP ----------------
__global__ void classifier(const float* __restrict__ pooled,
                           const float* __restrict__ w1, const float* __restrict__ b1,
                           const float* __restrict__ w2, const float* __restrict__ b2,
                           const float* __restrict__ w3, const float* __restrict__ b3,
                           float* __restrict__ out) {
    const int g = blockIdx.x;
    __shared__ float ph[512];
    __shared__ float o1[256];
    __shared__ float o2[64];
    const int t = threadIdx.x;  // 256 threads
    ph[t] = pooled[g * 512 + t];
    ph[t + 256] = pooled[g * 512 + 256 + t];
    __syncthreads();
    float s = 0.f;
    for (int k = 0; k < 512; ++k) s += ph[k] * w1[k * 256 + t];
    o1[t] = fmaxf(s + b1[t], 0.f);
    __syncthreads();
    if (t < 64) {
        float s2 = 0.f;
        for (int k = 0; k < 256; ++k) s2 += o1[k] * w2[k * 64 + t];
        o2[t] = fmaxf(s2 + b2[t], 0.f);
    }
    __syncthreads();
    if (t < 64) {
        float v = o2[t] * w3[t];
        for (int off = 32; off; off >>= 1) v += __shfl_down(v, off);
        if (t == 0) out[g] = v + b3[0];
    }
}

extern "C" void kernel_launch(void* const* d_in, const int* in_sizes, int n_in,
                              void* d_out, int out_size, void* d_ws, size_t ws_size,
                              hipStream_t stream) {
    (void)in_sizes; (void)n_in; (void)out_size; (void)ws_size;
    const float* x0 = (const float*)d_in[0];
    const int* eidx = (const int*)d_in[1];
    const int* batch = (const int*)d_in[2];
    const int* srcI = eidx;            // edge_index[0] = src
    const int* dstI = eidx + NE;       // edge_index[1] = dst

    char* ws = (char*)d_ws;
    size_t off = 0;
    auto alloc = [&](size_t bytes) -> void* {
        void* p = ws + off;
        off += (bytes + 255) & ~(size_t)255;
        return p;
    };
    _Float16* xh = (_Float16*)alloc((size_t)NP * 256 * 2);
    float* AB = (float*)alloc((size_t)NP * 512 * 4);
    float* y  = (float*)alloc((size_t)NP * 256 * 4);
    _Float16* WcT = (_Float16*)alloc(512 * 256 * 2);
    _Float16* w2T = (_Float16*)alloc(256 * 256 * 2);
    float* pooled = (float*)alloc(64 * 512 * 4);
    int* hist = (int*)alloc(NN * 4);
    int* se2 = (int*)alloc(NE * 4);
    int* de2 = (int*)alloc(NE * 4);

    const float* lw[3][4] = {
        {(const float*)d_in[3],  (const float*)d_in[4],  (const float*)d_in[5],  (const float*)d_in[6]},
        {(const float*)d_in[7],  (const float*)d_in[8],  (const float*)d_in[9],  (const float*)d_in[10]},
        {(const float*)d_in[11], (const float*)d_in[12], (const float*)d_in[13], (const float*)d_in[14]},
    };

    // sort edges by dst (once, reused all layers)
    hipMemsetAsync(hist, 0, NN * 4, stream);
    hist_kernel<<<dim3((NE + 255) / 256), dim3(256), 0, stream>>>(dstI, hist);
    scan_kernel<<<dim3(1), dim3(256), 0, stream>>>(hist, hist);  // in-place exclusive scan
    scatter_kernel<<<dim3((NE + 255) / 256), dim3(256), 0, stream>>>(srcI, dstI, hist, se2, de2);

    conv_rows<<<dim3(512), dim3(256), 0, stream>>>(x0, 128, xh);

    for (int l = 0; l < 3; ++l) {
        const int C = (l == 0) ? 128 : 256;
        prep_weights<<<dim3(256), dim3(256), 0, stream>>>(lw[l][0], lw[l][2], C, WcT, w2T);
        if (C == 128)
            node_gemm<128><<<dim3(NP / 64, 4), dim3(256), 0, stream>>>(xh, WcT, lw[l][1], AB);
        else
            node_gemm<256><<<dim3(NP / 64, 4), dim3(256), 0, stream>>>(xh, WcT, lw[l][1], AB);
        hipMemsetAsync(y, 0, (size_t)NP * 256 * 4, stream);
        edge_gemm<<<dim3(NE / EB), dim3(256), 0, stream>>>(AB, se2, de2, w2T, lw[l][3], y);
        if (l < 2)
            conv_rows<<<dim3(1024), dim3(256), 0, stream>>>(y, 256, xh);
    }

    pool_kernel<<<dim3(NG), dim3(256), 0, stream>>>(y, batch, pooled);
    classifier<<<dim3(NG), dim3(256), 0, stream>>>(pooled,
        (const float*)d_in[15], (const float*)d_in[16],
        (const float*)d_in[17], (const float*)d_in[18],
        (const float*)d_in[19], (const float*)d_in[20], (float*)d_out);
}

// Round 5
// 358.092 us; speedup vs baseline: 3.6203x; 1.0914x over previous
//
#include <hip/hip_runtime.h>

// PocketGNN on MI355X — round 5.
// - EdgeConv first matmul on nodes: A = x@(w1t-w1b)+b1 (f32), B = x@w1b (f16)
//   A gathered by dst (sorted -> cache-friendly, f32 keeps precision);
//   B gathered by src (random) -> f16 halves the hot random traffic; B=5MB ~ one XCD L2
// - XCD-chunked bijective block swizzle on edge_gemm: contiguous edge range per XCD
//   -> B mostly L2-resident, A segments XCD-local
// - h@w2 f16 single-MFMA; edges dst-sorted; permuted LDS rows so each lane's 16 acc
//   values are 16 consecutive sorted edges -> register segment-max, few atomics
// - launch_bounds(256,4): 128-reg budget (acc 64 + ~50 working), 16 waves/CU;
//   stage issues 16 loads per 8-edge batch before converting (2 batches, deep MLP)

#define NN 10000
#define NE 160000
#define NG 64
#define NP 10048  // nodes padded to 64
#define EB 64     // edges per block

typedef __attribute__((ext_vector_type(8))) _Float16 f16x8;
typedef __attribute__((ext_vector_type(4))) _Float16 f16x4;
typedef __attribute__((ext_vector_type(4))) float f32x4;

// ---------------- edge sort by dst (counting sort) ----------------
__global__ void hist_kernel(const int* __restrict__ dstI, int* __restrict__ hist) {
    int i = blockIdx.x * blockDim.x + threadIdx.x;
    if (i < NE) atomicAdd(&hist[dstI[i]], 1);
}

// in-place safe: cursor may alias hist
__global__ void scan_kernel(const int* __restrict__ hist, int* __restrict__ cursor) {
    __shared__ int sums[256];
    const int t = threadIdx.x;
    const int per = (NN + 255) / 256;  // 40
    const int lo = t * per, hi = (lo + per < NN) ? lo + per : NN;
    int s = 0;
    for (int i = lo; i < hi; ++i) s += hist[i];
    sums[t] = s;
    __syncthreads();
    for (int ofs = 1; ofs < 256; ofs <<= 1) {
        int add = (t >= ofs) ? sums[t - ofs] : 0;
        __syncthreads();
        sums[t] += add;
        __syncthreads();
    }
    int run = sums[t] - s;  // exclusive prefix
    for (int i = lo; i < hi; ++i) {
        int h = hist[i];      // read BEFORE aliased write
        cursor[i] = run;
        run += h;
    }
}

__global__ void scatter_kernel(const int* __restrict__ srcI, const int* __restrict__ dstI,
                               int* __restrict__ cursor,
                               int* __restrict__ se2, int* __restrict__ de2) {
    int i = blockIdx.x * blockDim.x + threadIdx.x;
    if (i < NE) {
        int d = dstI[i];
        int p = atomicAdd(&cursor[d], 1);
        se2[p] = srcI[i];
        de2[p] = d;
    }
}

// ---------------- weight prep ----------------
// WcT [512][C]: rows 0..255 = (w1t-w1b)^T, 256..511 = w1b^T.  w2T [256][256] = w2^T.
__global__ void prep_weights(const float* __restrict__ w1, const float* __restrict__ w2, int C,
                             _Float16* __restrict__ WcT, _Float16* __restrict__ w2T) {
    int total1 = 512 * C;
    int total = total1 + 256 * 256;
    for (int i = blockIdx.x * blockDim.x + threadIdx.x; i < total; i += gridDim.x * blockDim.x) {
        if (i < total1) {
            int n = i / C, k = i - n * C;
            float v = (n < 256) ? (w1[k * 256 + n] - w1[(C + k) * 256 + n])
                                : w1[(C + k) * 256 + (n - 256)];
            WcT[n * C + k] = (_Float16)v;
        } else {
            int j = i - total1;
            int n = j >> 8, k = j & 255;
            w2T[n * 256 + k] = (_Float16)w2[k * 256 + n];
        }
    }
}

// fp32 [N,C] -> f16 [NP,C], pad rows zeroed (vectorized x4)
template <int C>
__global__ void conv_rows(const float* __restrict__ src, _Float16* __restrict__ xh) {
    const int total4 = NP * C / 4;
    const int c4 = C / 4;
    for (int i4 = blockIdx.x * blockDim.x + threadIdx.x; i4 < total4; i4 += gridDim.x * blockDim.x) {
        const int row = i4 / c4;
        f16x4 o;
        if (row < NN) {
            float4 v = ((const float4*)src)[i4];
            o[0] = (_Float16)v.x; o[1] = (_Float16)v.y;
            o[2] = (_Float16)v.z; o[3] = (_Float16)v.w;
        } else {
            o[0] = o[1] = o[2] = o[3] = (_Float16)0.f;
        }
        ((f16x4*)xh)[i4] = o;
    }
}

// ---------------- node GEMM: [A | B] = x @ [Wc_A | Wc_B]; A f32 (+b1), B f16 ----------------
template <int C>
__global__ __launch_bounds__(256) void node_gemm(
    const _Float16* __restrict__ xh, const _Float16* __restrict__ WT,
    const float* __restrict__ b1, float* __restrict__ Af, _Float16* __restrict__ Bh) {
    const int wave = threadIdx.x >> 6, lane = threadIdx.x & 63;
    const int lrow = lane & 15, lk = (lane >> 4) * 8;
    const int r0 = blockIdx.x * 64;
    const int c0 = blockIdx.y * 128 + wave * 32;

    f32x4 acc[4][2] = {};
#pragma unroll
    for (int kk = 0; kk < C; kk += 32) {
        f16x8 ah[4];
#pragma unroll
        for (int m = 0; m < 4; ++m)
            ah[m] = *(const f16x8*)(xh + (size_t)(r0 + m * 16 + lrow) * C + kk + lk);
#pragma unroll
        for (int t = 0; t < 2; ++t) {
            f16x8 bh = *(const f16x8*)(WT + (size_t)(c0 + t * 16 + lrow) * C + kk + lk);
#pragma unroll
            for (int m = 0; m < 4; ++m)
                acc[m][t] = __builtin_amdgcn_mfma_f32_16x16x32_f16(ah[m], bh, acc[m][t], 0, 0, 0);
        }
    }
    if (blockIdx.y < 2) {  // A half: +bias, f32
#pragma unroll
        for (int t = 0; t < 2; ++t) {
            const int col = c0 + t * 16 + lrow;
            const float bias = b1[col];
#pragma unroll
            for (int m = 0; m < 4; ++m)
#pragma unroll
                for (int j = 0; j < 4; ++j) {
                    const int row = r0 + m * 16 + (lane >> 4) * 4 + j;
                    Af[(size_t)row * 256 + col] = acc[m][t][j] + bias;
                }
        }
    } else {  // B half: f16
#pragma unroll
        for (int t = 0; t < 2; ++t) {
            const int col = c0 - 256 + t * 16 + lrow;
#pragma unroll
            for (int m = 0; m < 4; ++m)
#pragma unroll
                for (int j = 0; j < 4; ++j) {
                    const int row = r0 + m * 16 + (lane >> 4) * 4 + j;
                    Bh[(size_t)row * 256 + col] = (_Float16)acc[m][t][j];
                }
        }
    }
}

// ---------------- fused edge kernel (sorted-by-dst edges) ----------------
// Edge e_local sits in LDS row perm(e_local) (bit-swap involution):
//   e = (m<<4)|(g<<2)|j  <->  row = (g<<4)|(m<<2)|j
// so lane g's acc[m][t][j] maps to edge g*16 + m*4 + j: 16 CONSECUTIVE sorted edges
// -> register segment-max, few atomics.
__global__ __launch_bounds__(256, 4) void edge_gemm(
    const float* __restrict__ Af, const _Float16* __restrict__ Bh,
    const int* __restrict__ se2, const int* __restrict__ de2,
    const _Float16* __restrict__ w2T,
    const float* __restrict__ b2, float* __restrict__ y) {
    __shared__ _Float16 hh[EB * 256];  // 32 KB, XOR-swizzled
    const int tid = threadIdx.x;
    const int wave = tid >> 6, lane = tid & 63;

    // XCD-chunked bijective swizzle (grid = 2500 = 8*312 + 4)
    const int orig = blockIdx.x;
    const int xcd = orig & 7, pos = orig >> 3;
    const int q = 2500 >> 3, r = 2500 & 7;  // 312, 4
    const int bid = (xcd < r ? xcd * (q + 1) : r * (q + 1) + (xcd - r) * q) + pos;
    const int e0 = bid * EB;
    const int ew = wave * 16;

    // ---- stage: h = relu(A[dst] + B[src]) -> f16 LDS at permuted row ----
    int se[16], de[16];
#pragma unroll
    for (int i = 0; i < 16; ++i) {
        se[i] = se2[e0 + ew + i];
        de[i] = de2[e0 + ew + i];
    }
#pragma unroll
    for (int b = 0; b < 2; ++b) {  // 8 edges/batch, 16 loads in flight
        float4 av[8];
        f16x4 bv[8];
#pragma unroll
        for (int i = 0; i < 8; ++i) {
            const int el = b * 8 + i;
            bv[i] = *(const f16x4*)(Bh + (size_t)se[el] * 256 + lane * 4);
            av[i] = *(const float4*)(Af + (size_t)de[el] * 256 + lane * 4);
        }
#pragma unroll
        for (int i = 0; i < 8; ++i) {
            const int el = b * 8 + i;  // local edge within wave, 0..15
            // row = (el>>2)*16 + wave*4 + (el&3)   (bit-swap involution)
            const int row = (el >> 2) * 16 + wave * 4 + (el & 3);
            f16x4 vh;
            vh[0] = (_Float16)fmaxf(av[i].x + (float)bv[i][0], 0.f);
            vh[1] = (_Float16)fmaxf(av[i].y + (float)bv[i][1], 0.f);
            vh[2] = (_Float16)fmaxf(av[i].z + (float)bv[i][2], 0.f);
            vh[3] = (_Float16)fmaxf(av[i].w + (float)bv[i][3], 0.f);
            const int idx = (row * 256 + lane * 4) ^ ((row & 7) << 3);
            *(f16x4*)(&hh[idx]) = vh;
        }
    }
    __syncthreads();

    // ---- gemm: M=64 (4 tiles), wave's N=64 (4 tiles), K=256 ----
    const int lrow = lane & 15, lk = (lane >> 4) * 8;
    const _Float16* wbase = w2T + (size_t)(wave * 64 + lrow) * 256 + lk;

    f32x4 acc[4][4] = {};
    for (int kk = 0; kk < 256; kk += 32) {
        f16x8 ah[4];
#pragma unroll
        for (int m = 0; m < 4; ++m) {
            const int row = m * 16 + lrow;
            const int idx = (row * 256 + kk + lk) ^ ((row & 7) << 3);
            ah[m] = *(const f16x8*)(&hh[idx]);
        }
#pragma unroll
        for (int t = 0; t < 4; ++t) {
            f16x8 bh = *(const f16x8*)(wbase + (size_t)(t * 16) * 256 + kk);
#pragma unroll
            for (int m = 0; m < 4; ++m)
                acc[m][t] = __builtin_amdgcn_mfma_f32_16x16x32_f16(ah[m], bh, acc[m][t], 0, 0, 0);
        }
    }

    // ---- epilogue: lane's 16 acc values = edges e0+g*16 .. +15; segment-max, atomics ----
    const int g = lane >> 4;
    int d[16];
#pragma unroll
    for (int k = 0; k < 16; ++k) d[k] = de2[e0 + g * 16 + k];
#pragma unroll
    for (int t = 0; t < 4; ++t) {
        const int col = wave * 64 + t * 16 + lrow;
        const float bias = b2[col];
        float run = acc[0][t][0] + bias;
        int dp = d[0];
#pragma unroll
        for (int k = 1; k < 16; ++k) {
            const float v = acc[k >> 2][t][k & 3] + bias;
            if (d[k] == dp) {
                run = fmaxf(run, v);
            } else {
                if (run > 0.f) atomicMax((int*)(y + (size_t)dp * 256 + col), __float_as_int(run));
                run = v;
                dp = d[k];
            }
        }
        if (run > 0.f) atomicMax((int*)(y + (size_t)dp * 256 + col), __float_as_int(run));
    }
}

// ---------------- per-graph mean+max pool ----------------
__global__ void pool_kernel(const float* __restrict__ y, const int* __restrict__ batch,
                            float* __restrict__ pooled) {
    const int g = blockIdx.x;
    __shared__ int slo, shi;
    if (threadIdx.x == 0) {
        int lo = 0, hi = NN;
        while (lo < hi) { int m = (lo + hi) >> 1; if (batch[m] < g) lo = m + 1; else hi = m; }
        slo = lo;
        int lo2 = lo, hi2 = NN;
        while (lo2 < hi2) { int m = (lo2 + hi2) >> 1; if (batch[m] < g + 1) lo2 = m + 1; else hi2 = m; }
        shi = lo2;
    }
    __syncthreads();
    const int lo = slo, hi = shi, c = threadIdx.x;
    float s0 = 0.f, s1 = 0.f, s2 = 0.f, s3 = 0.f;
    float m0 = 0.f, m1 = 0.f, m2 = 0.f, m3 = 0.f;  // y >= 0 -> 0 safe identity
    int n = lo;
    for (; n + 4 <= hi; n += 4) {
        float v0 = y[(size_t)(n + 0) * 256 + c];
        float v1 = y[(size_t)(n + 1) * 256 + c];
        float v2 = y[(size_t)(n + 2) * 256 + c];
        float v3 = y[(size_t)(n + 3) * 256 + c];
        s0 += v0; s1 += v1; s2 += v2; s3 += v3;
        m0 = fmaxf(m0, v0); m1 = fmaxf(m1, v1); m2 = fmaxf(m2, v2); m3 = fmaxf(m3, v3);
    }
    for (; n < hi; ++n) {
        float v = y[(size_t)n * 256 + c];
        s0 += v; m0 = fmaxf(m0, v);
    }
    const float s = (s0 + s1) + (s2 + s3);
    const float mx = fmaxf(fmaxf(m0, m1), fmaxf(m2, m3));
    const int cnt = hi - lo;
    pooled[g * 512 + c] = cnt ? s / (float)cnt : 0.f;
    pooled[g * 512 + 256 + c] = cnt ? mx : 0.f;
}

// ---------------- classifier MLP ----------------
__global__ void classifier(const float* __restrict__ pooled,
                           const float* __restrict__ w1, const float* __restrict__ b1,
                           const float* __restrict__ w2, const float* __restrict__ b2,
                           const float* __restrict__ w3, const float* __restrict__ b3,
                           float* __restrict__ out) {
    const int g = blockIdx.x;
    __shared__ float ph[512];
    __shared__ float o1[256];
    __shared__ float o2[64];
    const int t = threadIdx.x;  // 256 threads
    ph[t] = pooled[g * 512 + t];
    ph[t + 256] = pooled[g * 512 + 256 + t];
    __syncthreads();
    float s = 0.f;
    for (int k = 0; k < 512; ++k) s += ph[k] * w1[k * 256 + t];
    o1[t] = fmaxf(s + b1[t], 0.f);
    __syncthreads();
    if (t < 64) {
        float s2 = 0.f;
        for (int k = 0; k < 256; ++k) s2 += o1[k] * w2[k * 64 + t];
        o2[t] = fmaxf(s2 + b2[t], 0.f);
    }
    __syncthreads();
    if (t < 64) {
        float v = o2[t] * w3[t];
        for (int off = 32; off; off >>= 1) v += __shfl_down(v, off);
        if (t == 0) out[g] = v + b3[0];
    }
}

extern "C" void kernel_launch(void* const* d_in, const int* in_sizes, int n_in,
                              void* d_out, int out_size, void* d_ws, size_t ws_size,
                              hipStream_t stream) {
    (void)in_sizes; (void)n_in; (void)out_size; (void)ws_size;
    const float* x0 = (const float*)d_in[0];
    const int* eidx = (const int*)d_in[1];
    const int* batch = (const int*)d_in[2];
    const int* srcI = eidx;            // edge_index[0] = src
    const int* dstI = eidx + NE;       // edge_index[1] = dst

    char* ws = (char*)d_ws;
    size_t off = 0;
    auto alloc = [&](size_t bytes) -> void* {
        void* p = ws + off;
        off += (bytes + 255) & ~(size_t)255;
        return p;
    };
    _Float16* xh = (_Float16*)alloc((size_t)NP * 256 * 2);
    float* Af = (float*)alloc((size_t)NP * 256 * 4);
    _Float16* Bh = (_Float16*)alloc((size_t)NP * 256 * 2);
    float* y  = (float*)alloc((size_t)NP * 256 * 4);
    _Float16* WcT = (_Float16*)alloc(512 * 256 * 2);
    _Float16* w2T = (_Float16*)alloc(256 * 256 * 2);
    float* pooled = (float*)alloc(64 * 512 * 4);
    int* hist = (int*)alloc(NN * 4);
    int* se2 = (int*)alloc(NE * 4);
    int* de2 = (int*)alloc(NE * 4);

    const float* lw[3][4] = {
        {(const float*)d_in[3],  (const float*)d_in[4],  (const float*)d_in[5],  (const float*)d_in[6]},
        {(const float*)d_in[7],  (const float*)d_in[8],  (const float*)d_in[9],  (const float*)d_in[10]},
        {(const float*)d_in[11], (const float*)d_in[12], (const float*)d_in[13], (const float*)d_in[14]},
    };

    // sort edges by dst (once, reused all layers)
    hipMemsetAsync(hist, 0, NN * 4, stream);
    hist_kernel<<<dim3((NE + 255) / 256), dim3(256), 0, stream>>>(dstI, hist);
    scan_kernel<<<dim3(1), dim3(256), 0, stream>>>(hist, hist);  // in-place exclusive scan
    scatter_kernel<<<dim3((NE + 255) / 256), dim3(256), 0, stream>>>(srcI, dstI, hist, se2, de2);

    conv_rows<128><<<dim3(1024), dim3(256), 0, stream>>>(x0, xh);

    for (int l = 0; l < 3; ++l) {
        const int C = (l == 0) ? 128 : 256;
        prep_weights<<<dim3(256), dim3(256), 0, stream>>>(lw[l][0], lw[l][2], C, WcT, w2T);
        if (C == 128)
            node_gemm<128><<<dim3(NP / 64, 4), dim3(256), 0, stream>>>(xh, WcT, lw[l][1], Af, Bh);
        else
            node_gemm<256><<<dim3(NP / 64, 4), dim3(256), 0, stream>>>(xh, WcT, lw[l][1], Af, Bh);
        hipMemsetAsync(y, 0, (size_t)NP * 256 * 4, stream);
        edge_gemm<<<dim3(NE / EB), dim3(256), 0, stream>>>(Af, Bh, se2, de2, w2T, lw[l][3], y);
        if (l < 2)
            conv_rows<256><<<dim3(1024), dim3(256), 0, stream>>>(y, xh);
    }

    pool_kernel<<<dim3(NG), dim3(256), 0, stream>>>(y, batch, pooled);
    classifier<<<dim3(NG), dim3(256), 0, stream>>>(pooled,
        (const float*)d_in[15], (const float*)d_in[16],
        (const float*)d_in[17], (const float*)d_in[18],
        (const float*)d_in[19], (const float*)d_in[20], (float*)d_out);
}